// Round 1
// baseline (198.494 us; speedup 1.0000x reference)
//
#include <hip/hip_runtime.h>
#include <hip/hip_bf16.h>

typedef __attribute__((ext_vector_type(4))) float f32x4;
typedef __attribute__((ext_vector_type(8))) short short8;

#define B_   4
#define T_   1024
#define H_   16
#define DK_  64
#define KDIM 1024

__device__ __forceinline__ unsigned short f2bf(float f){
  union { float f; unsigned int u; } a; a.f = f;
  unsigned int u = a.u;
  return (unsigned short)((u + 0x7FFFu + ((u >> 16) & 1u)) >> 16);
}

__device__ __forceinline__ void gload16(const void* g, void* l){
  __builtin_amdgcn_global_load_lds(
      (const __attribute__((address_space(1))) unsigned int*)g,
      (__attribute__((address_space(3))) unsigned int*)l,
      16, 0, 0);
}

// ---------------- fp32 -> bf16 conversion of x and the 4 weights ----------------
__global__ __launch_bounds__(256) void convert5(
    const float* __restrict__ x,  const float* __restrict__ wq,
    const float* __restrict__ wk, const float* __restrict__ wv,
    const float* __restrict__ wo,
    short* __restrict__ xb,  short* __restrict__ wqb,
    short* __restrict__ wkb, short* __restrict__ wvb, short* __restrict__ wob)
{
  int i = blockIdx.x * 256 + threadIdx.x;   // over 2M float4 chunks
  const float* s; short* d; int off;
  if (i < (1 << 20)) { s = x; d = xb; off = i; }
  else {
    int j = i - (1 << 20);
    int w = j >> 18;          // 0..3
    off = j & ((1 << 18) - 1);
    s = (w == 0) ? wq : (w == 1) ? wk : (w == 2) ? wv : wo;
    d = (w == 0) ? wqb : (w == 1) ? wkb : (w == 2) ? wvb : wob;
  }
  float4 v = ((const float4*)s)[off];
  ushort4 o;
  o.x = f2bf(v.x); o.y = f2bf(v.y); o.z = f2bf(v.z); o.w = f2bf(v.w);
  ((ushort4*)d)[off] = o;
}

// ---------------- shared GEMM core: C = A @ W^T, 128x128 tile, BK=32 ----------------
// A: (M,1024) bf16 row-major; W: (1024,1024) bf16 row-major (rows are output cols).
__device__ __forceinline__ void gemm_core(const short* __restrict__ A,
                                          const short* __restrict__ W,
                                          int m0, int n0,
                                          short* Als, short* Bls,
                                          f32x4 acc[4][4])
{
  const int tid = threadIdx.x;
  const int wv = tid >> 6, lane = tid & 63;
  const int lr = lane & 15, lq = lane >> 4;
  const int wr = wv >> 1, wc = wv & 1;
#pragma unroll
  for (int m = 0; m < 4; ++m)
#pragma unroll
    for (int n = 0; n < 4; ++n) acc[m][n] = (f32x4){0.f, 0.f, 0.f, 0.f};

  const int r0 = tid >> 2;           // staging: row within tile (per pass p: +64)
  const int c0 = (tid & 3) * 8;      // staging: col (8 bf16 = 16B)

  auto stage = [&](int buf, int ks) {
    const int k0 = ks * 32;
#pragma unroll
    for (int p = 0; p < 2; ++p) {
      const int r = p * 64 + r0;
      const short* ga = A + (size_t)(m0 + r) * KDIM + k0 + c0;
      const short* gb = W + (size_t)(n0 + r) * KDIM + k0 + c0;
      // wave-uniform LDS base; HW adds lane*16B (linear [128][32] layout)
      short* la = Als + buf * 4096 + p * 2048 + wv * 512;
      short* lb = Bls + buf * 4096 + p * 2048 + wv * 512;
      gload16(ga, la);
      gload16(gb, lb);
    }
  };

  stage(0, 0);
  __syncthreads();
  for (int ks = 0; ks < 32; ++ks) {
    const int cur = ks & 1;
    if (ks + 1 < 32) stage(cur ^ 1, ks + 1);
    const short* Ab = Als + cur * 4096;
    const short* Bb = Bls + cur * 4096;
    short8 af[4], bfr[4];
#pragma unroll
    for (int i = 0; i < 4; ++i) {
      af[i]  = *(const short8*)(Ab + (wr * 64 + i * 16 + lr) * 32 + lq * 8);
      bfr[i] = *(const short8*)(Bb + (wc * 64 + i * 16 + lr) * 32 + lq * 8);
    }
#pragma unroll
    for (int m = 0; m < 4; ++m)
#pragma unroll
      for (int n = 0; n < 4; ++n)
        acc[m][n] = __builtin_amdgcn_mfma_f32_16x16x32_bf16(af[m], bfr[n], acc[m][n], 0, 0, 0);
    __syncthreads();
  }
}

// ---------------- fused QKV projection ----------------
// grid (32, 24): y<8 -> Q, 8..15 -> K, 16..23 -> V (written transposed per head)
__global__ __launch_bounds__(256, 2) void gemm_qkv(
    const short* __restrict__ xb,
    const short* __restrict__ Wqb, const short* __restrict__ Wkb, const short* __restrict__ Wvb,
    short* __restrict__ Qb, short* __restrict__ Kb, short* __restrict__ VTb)
{
  __shared__ short Als[2 * 4096];
  __shared__ short Bls[2 * 4096];
  const int m0 = blockIdx.x * 128;
  const int by = blockIdx.y;
  const int wsel = by >> 3;
  const int n0 = (by & 7) * 128;
  const short* W = (wsel == 0) ? Wqb : (wsel == 1) ? Wkb : Wvb;
  f32x4 acc[4][4];
  gemm_core(xb, W, m0, n0, Als, Bls, acc);

  const int tid = threadIdx.x, lane = tid & 63, wv = tid >> 6;
  const int lr = lane & 15, lq = lane >> 4, wr = wv >> 1, wc = wv & 1;
  if (wsel < 2) {
    short* O = wsel ? Kb : Qb;
#pragma unroll
    for (int m = 0; m < 4; ++m)
#pragma unroll
      for (int n = 0; n < 4; ++n)
#pragma unroll
        for (int j = 0; j < 4; ++j) {
          int row = m0 + wr * 64 + m * 16 + lq * 4 + j;
          int col = n0 + wc * 64 + n * 16 + lr;
          O[(size_t)row * KDIM + col] = (short)f2bf(acc[m][n][j]);
        }
  } else {
    // V: write VT[b][h][d][t] so attention's PV B-operand is row-contiguous
#pragma unroll
    for (int m = 0; m < 4; ++m)
#pragma unroll
      for (int n = 0; n < 4; ++n) {
        int row = m0 + wr * 64 + m * 16 + lq * 4;   // 4 consecutive t's
        int col = n0 + wc * 64 + n * 16 + lr;
        int b = row >> 10, t = row & 1023, h = col >> 6, d = col & 63;
        ushort4 v;
        v.x = f2bf(acc[m][n][0]); v.y = f2bf(acc[m][n][1]);
        v.z = f2bf(acc[m][n][2]); v.w = f2bf(acc[m][n][3]);
        *(ushort4*)&VTb[(size_t)((b * 16 + h) * 64 + d) * 1024 + t] = v;
      }
  }
}

// ---------------- flash attention ----------------
// grid (16, 64): x = q-tile of 64 rows, y = b*16+h. 4 waves, 16 q-rows each.
__global__ __launch_bounds__(256) void attn_kern(
    const short* __restrict__ Qb, const short* __restrict__ Kb,
    const short* __restrict__ VTb, short* __restrict__ AOb)
{
  __shared__ short kl[64 * 64];       // [kv][d], XOR-swizzled rows
  __shared__ short vl[64 * 64];       // [d][kv], XOR-swizzled rows
  __shared__ short pl[4][16 * 64];    // per-wave P, XOR-swizzled rows
  const int bh = blockIdx.y;
  const int b = bh >> 4, h = bh & 15;
  const int q0 = blockIdx.x * 64;
  const int tid = threadIdx.x;
  const int wv = tid >> 6, lane = tid & 63;
  const int lr = lane & 15, lq = lane >> 4;

  // Q fragment: rows q0+wv*16+lr of head h, two K=32 chunks over d=64
  const short* Qrow = Qb + (size_t)(b * T_ + q0 + wv * 16 + lr) * KDIM + h * DK_;
  short8 qf[2];
  qf[0] = *(const short8*)(Qrow + lq * 8);
  qf[1] = *(const short8*)(Qrow + 32 + lq * 8);

  float m_r[4] = {-1e30f, -1e30f, -1e30f, -1e30f};
  float l_r[4] = {0.f, 0.f, 0.f, 0.f};
  f32x4 oacc[4];
#pragma unroll
  for (int i = 0; i < 4; ++i) oacc[i] = (f32x4){0.f, 0.f, 0.f, 0.f};

  const int skr = tid >> 3;          // staging row (per pass: +32)
  const int skc = (tid & 7) * 8;     // staging col, 8 bf16 chunks

  for (int kt = 0; kt < 16; ++kt) {
    const int kv0 = kt * 64;
#pragma unroll
    for (int p = 0; p < 2; ++p) {
      const int kr = p * 32 + skr;
      const int sc = skc ^ ((kr & 7) << 3);
      uint4 kval = *(const uint4*)(Kb + (size_t)(b * T_ + kv0 + kr) * KDIM + h * DK_ + skc);
      *(uint4*)&kl[kr * 64 + sc] = kval;
      uint4 vval = *(const uint4*)(VTb + (size_t)((b * 16 + h) * 64 + kr) * 1024 + kv0 + skc);
      *(uint4*)&vl[kr * 64 + sc] = vval;
    }
    __syncthreads();

    // S = Q K^T (4 kv-subtiles of 16)
    f32x4 s[4];
#pragma unroll
    for (int nt = 0; nt < 4; ++nt) {
      s[nt] = (f32x4){0.f, 0.f, 0.f, 0.f};
#pragma unroll
      for (int kk = 0; kk < 2; ++kk) {
        const int krow = nt * 16 + lr;
        const int cb = (kk * 32 + lq * 8) ^ ((krow & 7) << 3);
        short8 bfrag = *(const short8*)(kl + krow * 64 + cb);
        s[nt] = __builtin_amdgcn_mfma_f32_16x16x32_bf16(qf[kk], bfrag, s[nt], 0, 0, 0);
      }
    }

    // online softmax; row j of this lane = q-row lq*4+j, cols nt*16+lr
#pragma unroll
    for (int j = 0; j < 4; ++j) {
      float s0 = s[0][j] * 0.125f, s1 = s[1][j] * 0.125f;
      float s2 = s[2][j] * 0.125f, s3 = s[3][j] * 0.125f;
      float mx = fmaxf(fmaxf(s0, s1), fmaxf(s2, s3));
      mx = fmaxf(mx, __shfl_xor(mx, 1));
      mx = fmaxf(mx, __shfl_xor(mx, 2));
      mx = fmaxf(mx, __shfl_xor(mx, 4));
      mx = fmaxf(mx, __shfl_xor(mx, 8));
      const float mn = fmaxf(m_r[j], mx);
      const float al = __expf(m_r[j] - mn);
      m_r[j] = mn;
      float p0 = __expf(s0 - mn), p1 = __expf(s1 - mn);
      float p2 = __expf(s2 - mn), p3 = __expf(s3 - mn);
      float rs = p0 + p1 + p2 + p3;
      rs += __shfl_xor(rs, 1);
      rs += __shfl_xor(rs, 2);
      rs += __shfl_xor(rs, 4);
      rs += __shfl_xor(rs, 8);
      l_r[j] = l_r[j] * al + rs;
#pragma unroll
      for (int nt = 0; nt < 4; ++nt) oacc[nt][j] *= al;
      const int pr = lq * 4 + j;
      const int swz = (pr & 7) << 3;
      pl[wv][pr * 64 + ((0 * 16 + lr) ^ swz)] = (short)f2bf(p0);
      pl[wv][pr * 64 + ((1 * 16 + lr) ^ swz)] = (short)f2bf(p1);
      pl[wv][pr * 64 + ((2 * 16 + lr) ^ swz)] = (short)f2bf(p2);
      pl[wv][pr * 64 + ((3 * 16 + lr) ^ swz)] = (short)f2bf(p3);
    }
    __syncthreads();

    // O += P V
    short8 pf[2];
#pragma unroll
    for (int kk = 0; kk < 2; ++kk)
      pf[kk] = *(const short8*)(pl[wv] + lr * 64 + ((kk * 32 + lq * 8) ^ ((lr & 7) << 3)));
#pragma unroll
    for (int nt = 0; nt < 4; ++nt) {
#pragma unroll
      for (int kk = 0; kk < 2; ++kk) {
        const int vrow = nt * 16 + lr;
        const int cb = (kk * 32 + lq * 8) ^ ((vrow & 7) << 3);
        short8 vf = *(const short8*)(vl + vrow * 64 + cb);
        oacc[nt] = __builtin_amdgcn_mfma_f32_16x16x32_bf16(pf[kk], vf, oacc[nt], 0, 0, 0);
      }
    }
    __syncthreads();
  }

  // epilogue: normalize and store bf16
#pragma unroll
  for (int nt = 0; nt < 4; ++nt) {
#pragma unroll
    for (int j = 0; j < 4; ++j) {
      const int row = q0 + wv * 16 + lq * 4 + j;
      const int col = h * DK_ + nt * 16 + lr;
      AOb[(size_t)(b * T_ + row) * KDIM + col] = (short)f2bf(oacc[nt][j] / l_r[j]);
    }
  }
}

// ---------------- output projection + bias (fp32 out) ----------------
__global__ __launch_bounds__(256, 2) void gemm_out(
    const short* __restrict__ AOb, const short* __restrict__ Wob,
    const float* __restrict__ bias, float* __restrict__ out)
{
  __shared__ short Als[2 * 4096];
  __shared__ short Bls[2 * 4096];
  const int m0 = blockIdx.x * 128;
  const int n0 = blockIdx.y * 128;
  f32x4 acc[4][4];
  gemm_core(AOb, Wob, m0, n0, Als, Bls, acc);

  const int tid = threadIdx.x, lane = tid & 63, wv = tid >> 6;
  const int lr = lane & 15, lq = lane >> 4, wr = wv >> 1, wc = wv & 1;
#pragma unroll
  for (int m = 0; m < 4; ++m)
#pragma unroll
    for (int n = 0; n < 4; ++n) {
      int col = n0 + wc * 64 + n * 16 + lr;
      float bv = bias[col];
#pragma unroll
      for (int j = 0; j < 4; ++j) {
        int row = m0 + wr * 64 + m * 16 + lq * 4 + j;
        out[(size_t)row * KDIM + col] = acc[m][n][j] + bv;
      }
    }
}

extern "C" void kernel_launch(void* const* d_in, const int* in_sizes, int n_in,
                              void* d_out, int out_size, void* d_ws, size_t ws_size,
                              hipStream_t stream) {
  const float* x  = (const float*)d_in[0];
  const float* Wq = (const float*)d_in[1];
  const float* Wk = (const float*)d_in[2];
  const float* Wv = (const float*)d_in[3];
  const float* Wo = (const float*)d_in[4];
  const float* bo = (const float*)d_in[5];

  short* ws = (short*)d_ws;
  short* xb  = ws;                       // 4M shorts
  short* Wqb = ws + 4194304;             // 1M each
  short* Wkb = ws + 5242880;
  short* Wvb = ws + 6291456;
  short* Wob = ws + 7340032;
  short* Qb  = ws + 8388608;             // 4M each
  short* Kb  = ws + 12582912;
  short* VTb = ws + 16777216;
  short* AOb = ws + 20971520;            // total 48 MB

  convert5<<<8192, 256, 0, stream>>>(x, Wq, Wk, Wv, Wo, xb, Wqb, Wkb, Wvb, Wob);
  gemm_qkv<<<dim3(32, 24), 256, 0, stream>>>(xb, Wqb, Wkb, Wvb, Qb, Kb, VTb);
  attn_kern<<<dim3(16, 64), 256, 0, stream>>>(Qb, Kb, VTb, AOb);
  gemm_out<<<dim3(32, 8), 256, 0, stream>>>(AOb, Wob, bo, (float*)d_out);
}

// Round 2
// 186.091 us; speedup vs baseline: 1.0666x; 1.0666x over previous
//
#include <hip/hip_runtime.h>
#include <hip/hip_bf16.h>

typedef __attribute__((ext_vector_type(4))) float f32x4;
typedef __attribute__((ext_vector_type(8))) short short8;

#define B_   4
#define T_   1024
#define H_   16
#define DK_  64
#define KDIM 1024

// Q pre-scale: 1/sqrt(d_k) * log2(e) so attention works in exp2 domain
#define QSCALE 0.18033688011112042f

__device__ __forceinline__ unsigned short f2bf(float f){
  union { float f; unsigned int u; } a; a.f = f;
  unsigned int u = a.u;
  return (unsigned short)((u + 0x7FFFu + ((u >> 16) & 1u)) >> 16);
}

__device__ __forceinline__ unsigned short f2bf_rn(float f){
  union { __hip_bfloat16 h; unsigned short u; } cv;
  cv.h = __float2bfloat16(f);
  return cv.u;
}

__device__ __forceinline__ void gload16(const void* g, void* l){
  __builtin_amdgcn_global_load_lds(
      (const __attribute__((address_space(1))) unsigned int*)g,
      (__attribute__((address_space(3))) unsigned int*)l,
      16, 0, 0);
}

// ---------------- fp32 -> bf16 conversion of x and the 4 weights ----------------
__global__ __launch_bounds__(256) void convert5(
    const float* __restrict__ x,  const float* __restrict__ wq,
    const float* __restrict__ wk, const float* __restrict__ wv,
    const float* __restrict__ wo,
    short* __restrict__ xb,  short* __restrict__ wqb,
    short* __restrict__ wkb, short* __restrict__ wvb, short* __restrict__ wob)
{
  int i = blockIdx.x * 256 + threadIdx.x;   // over 2M float4 chunks
  const float* s; short* d; int off;
  if (i < (1 << 20)) { s = x; d = xb; off = i; }
  else {
    int j = i - (1 << 20);
    int w = j >> 18;          // 0..3
    off = j & ((1 << 18) - 1);
    s = (w == 0) ? wq : (w == 1) ? wk : (w == 2) ? wv : wo;
    d = (w == 0) ? wqb : (w == 1) ? wkb : (w == 2) ? wvb : wob;
  }
  float4 v = ((const float4*)s)[off];
  ushort4 o;
  o.x = f2bf(v.x); o.y = f2bf(v.y); o.z = f2bf(v.z); o.w = f2bf(v.w);
  ((ushort4*)d)[off] = o;
}

// ---------------- shared GEMM core: C = A @ W^T, 128x128 tile, BK=32 ----------------
__device__ __forceinline__ void gemm_core(const short* __restrict__ A,
                                          const short* __restrict__ W,
                                          int m0, int n0,
                                          short* Als, short* Bls,
                                          f32x4 acc[4][4])
{
  const int tid = threadIdx.x;
  const int wv = tid >> 6, lane = tid & 63;
  const int lr = lane & 15, lq = lane >> 4;
  const int wr = wv >> 1, wc = wv & 1;
#pragma unroll
  for (int m = 0; m < 4; ++m)
#pragma unroll
    for (int n = 0; n < 4; ++n) acc[m][n] = (f32x4){0.f, 0.f, 0.f, 0.f};

  const int r0 = tid >> 2;
  const int c0 = (tid & 3) * 8;

  auto stage = [&](int buf, int ks) {
    const int k0 = ks * 32;
#pragma unroll
    for (int p = 0; p < 2; ++p) {
      const int r = p * 64 + r0;
      const short* ga = A + (size_t)(m0 + r) * KDIM + k0 + c0;
      const short* gb = W + (size_t)(n0 + r) * KDIM + k0 + c0;
      short* la = Als + buf * 4096 + p * 2048 + wv * 512;
      short* lb = Bls + buf * 4096 + p * 2048 + wv * 512;
      gload16(ga, la);
      gload16(gb, lb);
    }
  };

  stage(0, 0);
  __syncthreads();
  for (int ks = 0; ks < 32; ++ks) {
    const int cur = ks & 1;
    if (ks + 1 < 32) stage(cur ^ 1, ks + 1);
    const short* Ab = Als + cur * 4096;
    const short* Bb = Bls + cur * 4096;
    short8 af[4], bfr[4];
#pragma unroll
    for (int i = 0; i < 4; ++i) {
      af[i]  = *(const short8*)(Ab + (wr * 64 + i * 16 + lr) * 32 + lq * 8);
      bfr[i] = *(const short8*)(Bb + (wc * 64 + i * 16 + lr) * 32 + lq * 8);
    }
#pragma unroll
    for (int m = 0; m < 4; ++m)
#pragma unroll
      for (int n = 0; n < 4; ++n)
        acc[m][n] = __builtin_amdgcn_mfma_f32_16x16x32_bf16(af[m], bfr[n], acc[m][n], 0, 0, 0);
    __syncthreads();
  }
}

// ---------------- fused QKV projection ----------------
__global__ __launch_bounds__(256, 2) void gemm_qkv(
    const short* __restrict__ xb,
    const short* __restrict__ Wqb, const short* __restrict__ Wkb, const short* __restrict__ Wvb,
    short* __restrict__ Qb, short* __restrict__ Kb, short* __restrict__ VTb)
{
  __shared__ short Als[2 * 4096];
  __shared__ short Bls[2 * 4096];
  const int m0 = blockIdx.x * 128;
  const int by = blockIdx.y;
  const int wsel = by >> 3;
  const int n0 = (by & 7) * 128;
  const short* W = (wsel == 0) ? Wqb : (wsel == 1) ? Wkb : Wvb;
  f32x4 acc[4][4];
  gemm_core(xb, W, m0, n0, Als, Bls, acc);

  const int tid = threadIdx.x, lane = tid & 63, wv = tid >> 6;
  const int lr = lane & 15, lq = lane >> 4, wr = wv >> 1, wc = wv & 1;
  if (wsel < 2) {
    short* O = wsel ? Kb : Qb;
    const float sc = wsel ? 1.0f : QSCALE;   // Q carries softmax scale in log2 domain
#pragma unroll
    for (int m = 0; m < 4; ++m)
#pragma unroll
      for (int n = 0; n < 4; ++n)
#pragma unroll
        for (int j = 0; j < 4; ++j) {
          int row = m0 + wr * 64 + m * 16 + lq * 4 + j;
          int col = n0 + wc * 64 + n * 16 + lr;
          O[(size_t)row * KDIM + col] = (short)f2bf(acc[m][n][j] * sc);
        }
  } else {
    // V: write VT[b][h][d][t]
#pragma unroll
    for (int m = 0; m < 4; ++m)
#pragma unroll
      for (int n = 0; n < 4; ++n) {
        int row = m0 + wr * 64 + m * 16 + lq * 4;
        int col = n0 + wc * 64 + n * 16 + lr;
        int b = row >> 10, t = row & 1023, h = col >> 6, d = col & 63;
        ushort4 v;
        v.x = f2bf(acc[m][n][0]); v.y = f2bf(acc[m][n][1]);
        v.z = f2bf(acc[m][n][2]); v.w = f2bf(acc[m][n][3]);
        *(ushort4*)&VTb[(size_t)((b * 16 + h) * 64 + d) * 1024 + t] = v;
      }
  }
}

// ---------------- flash attention, swapped-operand form ----------------
// grid (16, 64): x = q-tile of 64 rows, y = b*16+h. 4 waves, 16 q-rows each.
// S^T = mfma(K,Q): lane owns q-row (lane&15); KVBLK=128, K/V double-buffered
// via global_load_lds with pre-swizzled source; 1 barrier per kv-tile.
__global__ __launch_bounds__(256) void attn_kern(
    const short* __restrict__ Qb, const short* __restrict__ Kb,
    const short* __restrict__ VTb, short* __restrict__ AOb)
{
  __shared__ __align__(16) short kl[2][128 * 64];   // [kv][d], XOR-swizzled cols
  __shared__ __align__(16) short vl[2][64 * 128];   // [d][kv], XOR-swizzled cols
  __shared__ __align__(16) short pl[4][16 * 64];    // per-wave P [q][kv-half]
  const int bh = blockIdx.y, b = bh >> 4, h = bh & 15;
  const int q0 = blockIdx.x * 64;
  const int tid = threadIdx.x, wv = tid >> 6, lane = tid & 63;
  const int lr = lane & 15, lq = lane >> 4;

  // Q fragment (already scaled by QSCALE): rows q0+wv*16+lr, d-chunks lq*8
  const short* Qrow = Qb + (size_t)(b * T_ + q0 + wv * 16 + lr) * KDIM + h * DK_;
  short8 qf0 = *(const short8*)(Qrow + lq * 8);
  short8 qf1 = *(const short8*)(Qrow + 32 + lq * 8);

  const short* Kbase = Kb + (size_t)(b * T_) * KDIM + h * DK_;
  const short* Vbase = VTb + (size_t)(bh * DK_) * 1024;

  const int krow_ = tid >> 3, kcol_ = (tid & 7) * 8;    // K pass: 32 rows x 64 cols
  const int vrow_ = tid >> 4, vcol_ = (tid & 15) * 8;   // V pass: 16 rows x 128 cols

  auto stage = [&](int buf, int kv0) {
#pragma unroll
    for (int p = 0; p < 4; ++p) {
      const int r = p * 32 + krow_;
      gload16(Kbase + (size_t)(kv0 + r) * KDIM + (kcol_ ^ ((r & 7) << 3)),
              &kl[buf][p * 2048 + wv * 512]);
    }
#pragma unroll
    for (int p = 0; p < 4; ++p) {
      const int r = p * 16 + vrow_;
      gload16(Vbase + (size_t)r * 1024 + kv0 + (vcol_ ^ ((r & 7) << 3)),
              &vl[buf][p * 2048 + wv * 512]);
    }
  };

  f32x4 oacc[4];
#pragma unroll
  for (int i = 0; i < 4; ++i) oacc[i] = (f32x4){0.f, 0.f, 0.f, 0.f};
  float m_r = -1e30f, l_r = 0.f;
  const int swq = (lr & 7) << 3;
  short* plw = pl[wv];

  int cur = 0;
  stage(0, 0);
  __syncthreads();

  for (int kt = 0; kt < 16384 / (128 * 1024 / T_); ++kt) { }  // (no-op; keep structure simple)

  for (int kt = 0; kt < 8; ++kt) {
    if (kt < 7) stage(cur ^ 1, (kt + 1) * 128);

    // ---- S^T[kv][q] = K Q^T (8 kv-subtiles x 2 d-chunks) ----
    f32x4 s[8];
#pragma unroll
    for (int nt = 0; nt < 8; ++nt) {
      const int kr = nt * 16 + lr;
      const int sw = (kr & 7) << 3;
      short8 kf0 = *(const short8*)&kl[cur][kr * 64 + ((lq * 8) ^ sw)];
      short8 kf1 = *(const short8*)&kl[cur][kr * 64 + ((32 + lq * 8) ^ sw)];
      f32x4 z = (f32x4){0.f, 0.f, 0.f, 0.f};
      z = __builtin_amdgcn_mfma_f32_16x16x32_bf16(kf0, qf0, z, 0, 0, 0);
      s[nt] = __builtin_amdgcn_mfma_f32_16x16x32_bf16(kf1, qf1, z, 0, 0, 0);
    }

    // ---- online softmax, row q = lr, 32 values in-lane + 2 shfl ----
    float t0, t1, mx;
    {
      float a0 = fmaxf(fmaxf(s[0][0], s[0][1]), fmaxf(s[0][2], s[0][3]));
      float a1 = fmaxf(fmaxf(s[1][0], s[1][1]), fmaxf(s[1][2], s[1][3]));
      float a2 = fmaxf(fmaxf(s[2][0], s[2][1]), fmaxf(s[2][2], s[2][3]));
      float a3 = fmaxf(fmaxf(s[3][0], s[3][1]), fmaxf(s[3][2], s[3][3]));
      float a4 = fmaxf(fmaxf(s[4][0], s[4][1]), fmaxf(s[4][2], s[4][3]));
      float a5 = fmaxf(fmaxf(s[5][0], s[5][1]), fmaxf(s[5][2], s[5][3]));
      float a6 = fmaxf(fmaxf(s[6][0], s[6][1]), fmaxf(s[6][2], s[6][3]));
      float a7 = fmaxf(fmaxf(s[7][0], s[7][1]), fmaxf(s[7][2], s[7][3]));
      t0 = fmaxf(fmaxf(a0, a1), fmaxf(a2, a3));
      t1 = fmaxf(fmaxf(a4, a5), fmaxf(a6, a7));
      mx = fmaxf(t0, t1);
    }
    mx = fmaxf(mx, __shfl_xor(mx, 16));
    mx = fmaxf(mx, __shfl_xor(mx, 32));
    if (!__all(mx <= m_r + 8.f)) {           // defer-max (T13), log2 domain
      const float mn = fmaxf(m_r, mx);
      const float al = exp2f(m_r - mn);
      l_r *= al;
#pragma unroll
      for (int nt = 0; nt < 4; ++nt)
#pragma unroll
        for (int j = 0; j < 4; ++j) oacc[nt][j] *= al;
      m_r = mn;
    }
    float rs = 0.f;
#pragma unroll
    for (int nt = 0; nt < 8; ++nt)
#pragma unroll
      for (int j = 0; j < 4; ++j) {
        float e = exp2f(s[nt][j] - m_r);
        s[nt][j] = e;
        rs += e;
      }
    rs += __shfl_xor(rs, 16);
    rs += __shfl_xor(rs, 32);
    l_r += rs;

    // ---- PV in two kv-halves through per-wave P buffer ----
#pragma unroll
    for (int half = 0; half < 2; ++half) {
#pragma unroll
      for (int nt = 0; nt < 4; ++nt) {
        f32x4 v = s[half * 4 + nt];
        ushort4 u;
        u.x = f2bf_rn(v[0]); u.y = f2bf_rn(v[1]);
        u.z = f2bf_rn(v[2]); u.w = f2bf_rn(v[3]);
        *(ushort4*)&plw[lr * 64 + ((nt * 16 + lq * 4) ^ swq)] = u;
      }
      asm volatile("s_waitcnt lgkmcnt(0)" ::: "memory");  // wave-local P visibility
      short8 pf0 = *(const short8*)&plw[lr * 64 + ((lq * 8) ^ swq)];
      short8 pf1 = *(const short8*)&plw[lr * 64 + ((32 + lq * 8) ^ swq)];
#pragma unroll
      for (int ntd = 0; ntd < 4; ++ntd) {
        const int vr = ntd * 16 + lr;
        const int sw = (vr & 7) << 3;
        short8 vf0 = *(const short8*)&vl[cur][vr * 128 + ((half * 64 + lq * 8) ^ sw)];
        short8 vf1 = *(const short8*)&vl[cur][vr * 128 + ((half * 64 + 32 + lq * 8) ^ sw)];
        oacc[ntd] = __builtin_amdgcn_mfma_f32_16x16x32_bf16(vf0, pf0, oacc[ntd], 0, 0, 0);
        oacc[ntd] = __builtin_amdgcn_mfma_f32_16x16x32_bf16(vf1, pf1, oacc[ntd], 0, 0, 0);
      }
    }
    __syncthreads();
    cur ^= 1;
  }

  // epilogue: O^T[d][q=lr] -> AOb[q][h*64+d], 4x ushort4
  const float inv = 1.0f / l_r;
#pragma unroll
  for (int nt = 0; nt < 4; ++nt) {
    ushort4 u;
    u.x = f2bf_rn(oacc[nt][0] * inv);
    u.y = f2bf_rn(oacc[nt][1] * inv);
    u.z = f2bf_rn(oacc[nt][2] * inv);
    u.w = f2bf_rn(oacc[nt][3] * inv);
    *(ushort4*)&AOb[(size_t)(b * T_ + q0 + wv * 16 + lr) * KDIM + h * DK_ + nt * 16 + lq * 4] = u;
  }
}

// ---------------- output projection + bias (fp32 out) ----------------
__global__ __launch_bounds__(256, 2) void gemm_out(
    const short* __restrict__ AOb, const short* __restrict__ Wob,
    const float* __restrict__ bias, float* __restrict__ out)
{
  __shared__ short Als[2 * 4096];
  __shared__ short Bls[2 * 4096];
  const int m0 = blockIdx.x * 128;
  const int n0 = blockIdx.y * 128;
  f32x4 acc[4][4];
  gemm_core(AOb, Wob, m0, n0, Als, Bls, acc);

  const int tid = threadIdx.x, lane = tid & 63, wv = tid >> 6;
  const int lr = lane & 15, lq = lane >> 4, wr = wv >> 1, wc = wv & 1;
#pragma unroll
  for (int m = 0; m < 4; ++m)
#pragma unroll
    for (int n = 0; n < 4; ++n) {
      int col = n0 + wc * 64 + n * 16 + lr;
      float bv = bias[col];
#pragma unroll
      for (int j = 0; j < 4; ++j) {
        int row = m0 + wr * 64 + m * 16 + lq * 4 + j;
        out[(size_t)row * KDIM + col] = acc[m][n][j] + bv;
      }
    }
}

extern "C" void kernel_launch(void* const* d_in, const int* in_sizes, int n_in,
                              void* d_out, int out_size, void* d_ws, size_t ws_size,
                              hipStream_t stream) {
  const float* x  = (const float*)d_in[0];
  const float* Wq = (const float*)d_in[1];
  const float* Wk = (const float*)d_in[2];
  const float* Wv = (const float*)d_in[3];
  const float* Wo = (const float*)d_in[4];
  const float* bo = (const float*)d_in[5];

  short* ws = (short*)d_ws;
  short* xb  = ws;
  short* Wqb = ws + 4194304;
  short* Wkb = ws + 5242880;
  short* Wvb = ws + 6291456;
  short* Wob = ws + 7340032;
  short* Qb  = ws + 8388608;
  short* Kb  = ws + 12582912;
  short* VTb = ws + 16777216;
  short* AOb = ws + 20971520;

  convert5<<<8192, 256, 0, stream>>>(x, Wq, Wk, Wv, Wo, xb, Wqb, Wkb, Wvb, Wob);
  gemm_qkv<<<dim3(32, 24), 256, 0, stream>>>(xb, Wqb, Wkb, Wvb, Qb, Kb, VTb);
  attn_kern<<<dim3(16, 64), 256, 0, stream>>>(Qb, Kb, VTb, AOb);
  gemm_out<<<dim3(32, 8), 256, 0, stream>>>(AOb, Wob, bo, (float*)d_out);
}